// Round 1
// baseline (87.952 us; speedup 1.0000x reference)
//
#include <hip/hip_runtime.h>
#include <stdint.h>
#include <math.h>

typedef __attribute__((ext_vector_type(8))) short bf16x8;
typedef __attribute__((ext_vector_type(4))) float f32x4;

#define HQ 2048
#define HK 2048
#define NH 8
#define ND 32
#define NC 256

union U8 { uint32_t u[4]; bf16x8 v; };

__device__ __forceinline__ uint16_t f2bf(float f) {
  uint32_t u = __float_as_uint(f);
  u += 0x7FFFu + ((u >> 16) & 1u);   // RNE
  return (uint16_t)(u >> 16);
}
__device__ __forceinline__ uint32_t pack2bf(float a, float b) {
  return (uint32_t)f2bf(a) | ((uint32_t)f2bf(b) << 16);
}
// 64B rows (32 bf16), 4 pieces of 16B; swizzle so 16-consecutive-row column
// reads AND the attention's permuted-row reads hit the 2-lane/bank floor.
__device__ __forceinline__ int swz64(int row, int piece) {
  int s = (((row >> 3) & 1) << 1) | ((row >> 1) & 1);
  return row * 64 + ((piece ^ s) << 4);
}
// 128B rows (64 bf16), 8 pieces of 16B
__device__ __forceinline__ int swzV(int row, int piece) {
  return row * 128 + ((piece ^ (row & 7)) << 4);
}
__device__ __forceinline__ f32x4 mfma32(bf16x8 a, bf16x8 b, f32x4 c) {
  return __builtin_amdgcn_mfma_f32_16x16x32_bf16(a, b, c, 0, 0, 0);
}

// ---------------- projections: q,k,v,g -----------------------------------
// grid 1024: bx&63 = Mblock(64), (bx>>6)&3 = Nblock(4), bx>>8 = proj id
__global__ __launch_bounds__(256) void proj_kernel(
    const float* __restrict__ qx, const float* __restrict__ kvx,
    const float* __restrict__ Wq, const float* __restrict__ Wk,
    const float* __restrict__ Wv, const float* __restrict__ Wg,
    const float* __restrict__ bg,
    uint16_t* __restrict__ q_p, uint16_t* __restrict__ k_p,
    uint16_t* __restrict__ v_p, float* __restrict__ g_ws)
{
  const int bx = blockIdx.x;
  const int Mb = bx & 63, Nb = (bx >> 6) & 3, p = bx >> 8;
  const int Mbase = Mb * 64, Nbase = Nb * 64;
  const float* X = (p == 0 || p == 3) ? qx : kvx;
  const float* W = (p == 0) ? Wq : (p == 1) ? Wk : (p == 2) ? Wv : Wg;

  __shared__ __align__(16) uint16_t smem[4096]; // 8KB: X tile | W tile
  uint16_t* sX = smem;
  uint16_t* sW = smem + 2048;

  const int tid = threadIdx.x;
  const int l = tid & 63, w = tid >> 6;
  const int qq = l & 15, g = l >> 4;
  const int row = tid >> 2, gp = tid & 3;

  f32x4 acc[4] = {};

  for (int ks = 0; ks < 8; ++ks) {
    const float* xs = X + (size_t)(Mbase + row) * 256 + ks * 32 + gp * 8;
    f32x4 x0 = *(const f32x4*)xs;
    f32x4 x1 = *(const f32x4*)(xs + 4);
    const float* ws_ = W + (size_t)(Nbase + row) * 256 + ks * 32 + gp * 8;
    f32x4 w0 = *(const f32x4*)ws_;
    f32x4 w1 = *(const f32x4*)(ws_ + 4);
    U8 ux, uw;
    ux.u[0] = pack2bf(x0[0], x0[1]); ux.u[1] = pack2bf(x0[2], x0[3]);
    ux.u[2] = pack2bf(x1[0], x1[1]); ux.u[3] = pack2bf(x1[2], x1[3]);
    uw.u[0] = pack2bf(w0[0], w0[1]); uw.u[1] = pack2bf(w0[2], w0[3]);
    uw.u[2] = pack2bf(w1[0], w1[1]); uw.u[3] = pack2bf(w1[2], w1[3]);
    __syncthreads();
    *(bf16x8*)((char*)sX + swz64(row, gp)) = ux.v;
    *(bf16x8*)((char*)sW + swz64(row, gp)) = uw.v;
    __syncthreads();
    bf16x8 a = *(bf16x8*)((char*)sX + swz64(w * 16 + qq, g));
#pragma unroll
    for (int nf = 0; nf < 4; ++nf) {
      bf16x8 bb = *(bf16x8*)((char*)sW + swz64(nf * 16 + qq, g));
      acc[nf] = mfma32(a, bb, acc[nf]);
    }
  }

  if (p == 2) {
    // transpose epilogue -> v_p[B,H,D,K]
    __syncthreads();
#pragma unroll
    for (int nf = 0; nf < 4; ++nf) {
      int n_loc = nf * 16 + qq;
#pragma unroll
      for (int r = 0; r < 4; ++r) {
        int m_loc = w * 16 + 4 * g + r;
        int byte = n_loc * 128 + ((((m_loc >> 3) ^ (n_loc & 7)) << 4)) + (m_loc & 7) * 2;
        *(uint16_t*)((char*)smem + byte) = f2bf(acc[nf][r]);
      }
    }
    __syncthreads();
    const int n_loc = tid >> 2, mp = tid & 3;
    const int ng = Nbase + n_loc;
    const int hh = ng >> 5, dd = ng & 31;
    const int bb_ = Mbase >> 11;
#pragma unroll
    for (int jj = 0; jj < 2; ++jj) {
      int piece = mp * 2 + jj;
      bf16x8 vv = *(bf16x8*)((char*)smem + n_loc * 128 + ((piece ^ (n_loc & 7)) << 4));
      int seq = (Mbase & 2047) + piece * 8;
      *(bf16x8*)(v_p + ((size_t)(bb_ * NH + hh) * ND + dd) * (size_t)HK + seq) = vv;
    }
    return;
  }

#pragma unroll
  for (int nf = 0; nf < 4; ++nf) {
    int n = Nbase + nf * 16 + qq;
#pragma unroll
    for (int r = 0; r < 4; ++r) {
      int m = Mbase + w * 16 + 4 * g + r;
      float val = acc[nf][r];
      if (p == 0) {
        val *= 0.17677669529663687f; // 1/sqrt(32)
        int bb_ = m >> 11, seq = m & 2047, hh = n >> 5, dd = n & 31;
        q_p[((size_t)(bb_ * NH + hh) * HQ + seq) * ND + dd] = f2bf(val);
      } else if (p == 1) {
        int bb_ = m >> 11, seq = m & 2047, hh = n >> 5, dd = n & 31;
        k_p[((size_t)(bb_ * NH + hh) * HK + seq) * ND + dd] = f2bf(val);
      } else { // p == 3 : gate
        g_ws[(size_t)m * NC + n] = 1.f / (1.f + __expf(-(val + bg[n])));
      }
    }
  }
}

// ---------------- fused attention -----------------------------------------
// grid 512: bx&1 = b, (bx>>1)&7 = h, bx>>4 = q-tile (64 rows)
__global__ __launch_bounds__(256) void attn_kernel(
    const uint16_t* __restrict__ q_p, const uint16_t* __restrict__ k_p,
    const uint16_t* __restrict__ v_p, const float* __restrict__ bias_mask,
    const float* __restrict__ bias_pair, const float* __restrict__ g_ws,
    uint16_t* __restrict__ o_g)
{
  const int bx = blockIdx.x;
  const int b = bx & 1, h = (bx >> 1) & 7, qt = bx >> 4;
  const int bh = b * NH + h;

  __shared__ __align__(16) char smem[9216];
  uint16_t* sK = (uint16_t*)smem;           // 4096 B
  uint16_t* sV = (uint16_t*)(smem + 4096);  // 4096 B

  const int tid = threadIdx.x;
  const int l = tid & 63, w = tid >> 6;
  const int qq = l & 15, g = l >> 4;
  const int q_glob = qt * 64 + w * 16 + qq;

  // Q B-fragment: B[d, q] = q[q, d]; lane: q = l&15, d = g*8..+7  (hoisted)
  bf16x8 qf = *(const bf16x8*)(q_p + ((size_t)bh * HQ + q_glob) * ND + g * 8);

  const int krow = tid >> 2, kgp = tid & 3;
  const int vrow = tid >> 3, vgp = tid & 7;

  f32x4 o0 = {}, o1 = {};
  float m_run = -1e30f, l_run = 0.f;

  const float* bp_base = bias_pair + ((size_t)h * HQ + q_glob) * (size_t)HK;
  const float* bm_base = bias_mask + (size_t)b * HK;

  for (int kt = 0; kt < HK / 64; ++kt) {
    bf16x8 kd = *(const bf16x8*)(k_p + ((size_t)bh * HK + kt * 64 + krow) * ND + kgp * 8);
    bf16x8 vd = *(const bf16x8*)(v_p + ((size_t)bh * ND + vrow) * (size_t)HK + kt * 64 + vgp * 8);
    __syncthreads();                         // prev iter's reads done
    *(bf16x8*)((char*)sK + swz64(krow, kgp)) = kd;
    *(bf16x8*)((char*)sV + swzV(vrow, vgp)) = vd;
    __syncthreads();

    // S^T = mfma(K_perm, Q). Row permutation perm(F,i)=32(F>>1)+8(i>>2)+4(F&1)+(i&3)
    // makes the D-layout of P identical to the PV B-fragment layout (no shuffles).
    f32x4 s[4];
#pragma unroll
    for (int F = 0; F < 4; ++F) {
      int kr = 32 * (F >> 1) + 8 * (qq >> 2) + 4 * (F & 1) + (qq & 3);
      bf16x8 af = *(bf16x8*)((char*)sK + swz64(kr, g));
      f32x4 z = {};
      s[F] = mfma32(af, qf, z);
    }
    // biases (k index for frag F, reg r: kt*64 + 32(F>>1) + 8g + 4(F&1) + r)
    float mloc = -1e30f;
#pragma unroll
    for (int F = 0; F < 4; ++F) {
      int kbase = kt * 64 + 32 * (F >> 1) + 8 * g + 4 * (F & 1);
      f32x4 bp = *(const f32x4*)(bp_base + kbase);
      f32x4 bm = *(const f32x4*)(bm_base + kbase);
#pragma unroll
      for (int r = 0; r < 4; ++r) {
        s[F][r] += bp[r] + bm[r];
        mloc = fmaxf(mloc, s[F][r]);
      }
    }
    mloc = fmaxf(mloc, __shfl_xor(mloc, 16, 64));
    mloc = fmaxf(mloc, __shfl_xor(mloc, 32, 64));
    float m_new = fmaxf(m_run, mloc);
    float alpha = __expf(m_run - m_new);
    float psum = 0.f;
    uint32_t pbk[4][2];
#pragma unroll
    for (int F = 0; F < 4; ++F) {
      float p0 = __expf(s[F][0] - m_new);
      float p1 = __expf(s[F][1] - m_new);
      float p2 = __expf(s[F][2] - m_new);
      float p3 = __expf(s[F][3] - m_new);
      psum += (p0 + p1) + (p2 + p3);
      pbk[F][0] = pack2bf(p0, p1);
      pbk[F][1] = pack2bf(p2, p3);
    }
    psum += __shfl_xor(psum, 16, 64);
    psum += __shfl_xor(psum, 32, 64);
    l_run = l_run * alpha + psum;
    m_run = m_new;
#pragma unroll
    for (int r = 0; r < 4; ++r) { o0[r] *= alpha; o1[r] *= alpha; }

    // O^T += V^T · P^T  (two k-chunks of 32, two d-halves)
#pragma unroll
    for (int c = 0; c < 2; ++c) {
      U8 bu;
      bu.u[0] = pbk[2 * c][0];     bu.u[1] = pbk[2 * c][1];
      bu.u[2] = pbk[2 * c + 1][0]; bu.u[3] = pbk[2 * c + 1][1];
      bf16x8 va0 = *(bf16x8*)((char*)sV + swzV(qq, 4 * c + g));
      bf16x8 va1 = *(bf16x8*)((char*)sV + swzV(16 + qq, 4 * c + g));
      o0 = mfma32(va0, bu.v, o0);
      o1 = mfma32(va1, bu.v, o1);
    }
  }

  // epilogue: /l, LDS transpose, gate, coalesced bf16 store
  __syncthreads();
  float inv = 1.f / l_run;
  float* se = (float*)smem + w * 576; // [16 q][36 d] per wave
#pragma unroll
  for (int r = 0; r < 4; ++r) {
    se[qq * 36 + 4 * g + r]      = o0[r] * inv;   // d = 4g+r
    se[qq * 36 + 16 + 4 * g + r] = o1[r] * inv;   // d = 16+4g+r
  }
  __syncthreads();
  const int qrow = l >> 2, pc = l & 3;
  const float* sr = (float*)smem + w * 576 + qrow * 36 + pc * 8;
  f32x4 x0 = *(const f32x4*)sr;
  f32x4 x1 = *(const f32x4*)(sr + 4);
  const int q_out = qt * 64 + w * 16 + qrow;
  const float* gp_ = g_ws + ((size_t)b * HQ + q_out) * NC + h * ND + pc * 8;
  f32x4 g0 = *(const f32x4*)gp_;
  f32x4 g1 = *(const f32x4*)(gp_ + 4);
  U8 ou;
  ou.u[0] = pack2bf(x0[0] * g0[0], x0[1] * g0[1]);
  ou.u[1] = pack2bf(x0[2] * g0[2], x0[3] * g0[3]);
  ou.u[2] = pack2bf(x1[0] * g1[0], x1[1] * g1[1]);
  ou.u[3] = pack2bf(x1[2] * g1[2], x1[3] * g1[3]);
  *(bf16x8*)(o_g + ((size_t)b * HQ + q_out) * NC + h * ND + pc * 8) = ou.v;
}

// ---------------- output projection ---------------------------------------
// grid 256: bx&63 = Mblock, bx>>6 = Nblock
__global__ __launch_bounds__(256) void outproj_kernel(
    const uint16_t* __restrict__ o_g, const float* __restrict__ Wo,
    const float* __restrict__ bo, float* __restrict__ out)
{
  const int bx = blockIdx.x;
  const int Mb = bx & 63, Nb = bx >> 6;
  const int Mbase = Mb * 64, Nbase = Nb * 64;
  __shared__ __align__(16) uint16_t smem2[4096];
  uint16_t* sA = smem2;
  uint16_t* sB = smem2 + 2048;
  const int tid = threadIdx.x;
  const int l = tid & 63, w = tid >> 6;
  const int qq = l & 15, g = l >> 4;
  const int row = tid >> 2, gp = tid & 3;
  f32x4 acc[4] = {};
  for (int ks = 0; ks < 8; ++ks) {
    bf16x8 av = *(const bf16x8*)(o_g + (size_t)(Mbase + row) * 256 + ks * 32 + gp * 8);
    const float* wsrc = Wo + (size_t)(Nbase + row) * 256 + ks * 32 + gp * 8;
    f32x4 w0 = *(const f32x4*)wsrc;
    f32x4 w1 = *(const f32x4*)(wsrc + 4);
    U8 uw;
    uw.u[0] = pack2bf(w0[0], w0[1]); uw.u[1] = pack2bf(w0[2], w0[3]);
    uw.u[2] = pack2bf(w1[0], w1[1]); uw.u[3] = pack2bf(w1[2], w1[3]);
    __syncthreads();
    *(bf16x8*)((char*)sA + swz64(row, gp)) = av;
    *(bf16x8*)((char*)sB + swz64(row, gp)) = uw.v;
    __syncthreads();
    bf16x8 a = *(bf16x8*)((char*)sA + swz64(w * 16 + qq, g));
#pragma unroll
    for (int nf = 0; nf < 4; ++nf) {
      bf16x8 bb = *(bf16x8*)((char*)sB + swz64(nf * 16 + qq, g));
      acc[nf] = mfma32(a, bb, acc[nf]);
    }
  }
#pragma unroll
  for (int nf = 0; nf < 4; ++nf) {
    int n = Nbase + nf * 16 + qq;
    float bias = bo[n];
#pragma unroll
    for (int r = 0; r < 4; ++r) {
      int m = Mbase + w * 16 + 4 * g + r;
      out[(size_t)m * NC + n] = acc[nf][r] + bias;
    }
  }
}

extern "C" void kernel_launch(void* const* d_in, const int* in_sizes, int n_in,
                              void* d_out, int out_size, void* d_ws, size_t ws_size,
                              hipStream_t stream) {
  (void)in_sizes; (void)n_in; (void)out_size; (void)ws_size;
  const float* qx        = (const float*)d_in[0];
  const float* kvx       = (const float*)d_in[1];
  const float* bias_mask = (const float*)d_in[2];
  const float* bias_pair = (const float*)d_in[3];
  const float* Wq        = (const float*)d_in[4];
  const float* Wk        = (const float*)d_in[5];
  const float* Wv        = (const float*)d_in[6];
  const float* Wo        = (const float*)d_in[7];
  const float* bo        = (const float*)d_in[8];
  const float* Wg        = (const float*)d_in[9];
  const float* bg        = (const float*)d_in[10];

  char* ws = (char*)d_ws;
  uint16_t* q_p  = (uint16_t*)(ws);                       // 2 MB
  uint16_t* k_p  = (uint16_t*)(ws + (2u << 20));          // 2 MB
  uint16_t* v_p  = (uint16_t*)(ws + (4u << 20));          // 2 MB  [B,H,D,K]
  float*    g_ws = (float*)   (ws + (6u << 20));          // 4 MB
  uint16_t* o_g  = (uint16_t*)(ws + (10u << 20));         // 2 MB
  float* out = (float*)d_out;

  proj_kernel<<<dim3(1024), dim3(256), 0, stream>>>(qx, kvx, Wq, Wk, Wv, Wg, bg,
                                                    q_p, k_p, v_p, g_ws);
  attn_kernel<<<dim3(512), dim3(256), 0, stream>>>(q_p, k_p, v_p, bias_mask,
                                                   bias_pair, g_ws, o_g);
  outproj_kernel<<<dim3(256), dim3(256), 0, stream>>>(o_g, Wo, bo, out);
}

// Round 2
// 80.816 us; speedup vs baseline: 1.0883x; 1.0883x over previous
//
#include <hip/hip_runtime.h>
#include <stdint.h>
#include <math.h>

typedef __attribute__((ext_vector_type(8))) short bf16x8;
typedef __attribute__((ext_vector_type(4))) float f32x4;

#define HQ 2048
#define HK 2048
#define NH 8
#define ND 32
#define NC 256

union U8 { uint32_t u[4]; bf16x8 v; };

__device__ __forceinline__ uint16_t f2bf(float f) {
  uint32_t u = __float_as_uint(f);
  u += 0x7FFFu + ((u >> 16) & 1u);   // RNE
  return (uint16_t)(u >> 16);
}
__device__ __forceinline__ uint32_t pack2bf(float a, float b) {
  return (uint32_t)f2bf(a) | ((uint32_t)f2bf(b) << 16);
}
// 64B rows (32 bf16), 4 pieces of 16B; swizzle so 16-consecutive-row column
// reads AND the attention's permuted-row reads hit the 2-lane/bank floor.
__device__ __forceinline__ int swz64(int row, int piece) {
  int s = (((row >> 3) & 1) << 1) | ((row >> 1) & 1);
  return row * 64 + ((piece ^ s) << 4);
}
// 128B rows (64 bf16), 8 pieces of 16B
__device__ __forceinline__ int swzV(int row, int piece) {
  return row * 128 + ((piece ^ (row & 7)) << 4);
}
__device__ __forceinline__ f32x4 mfma32(bf16x8 a, bf16x8 b, f32x4 c) {
  return __builtin_amdgcn_mfma_f32_16x16x32_bf16(a, b, c, 0, 0, 0);
}

// ---------------- projections: q,k,v,g -----------------------------------
// grid 1024: bx&63 = Mblock(64), (bx>>6)&3 = Nblock(4), bx>>8 = proj id
__global__ __launch_bounds__(256) void proj_kernel(
    const float* __restrict__ qx, const float* __restrict__ kvx,
    const float* __restrict__ Wq, const float* __restrict__ Wk,
    const float* __restrict__ Wv, const float* __restrict__ Wg,
    const float* __restrict__ bg,
    uint16_t* __restrict__ q_p, uint16_t* __restrict__ k_p,
    uint16_t* __restrict__ v_p, float* __restrict__ g_ws)
{
  const int bx = blockIdx.x;
  const int Mb = bx & 63, Nb = (bx >> 6) & 3, p = bx >> 8;
  const int Mbase = Mb * 64, Nbase = Nb * 64;
  const float* X = (p == 0 || p == 3) ? qx : kvx;
  const float* W = (p == 0) ? Wq : (p == 1) ? Wk : (p == 2) ? Wv : Wg;

  __shared__ __align__(16) uint16_t smem[4096]; // 8KB: X tile | W tile
  uint16_t* sX = smem;
  uint16_t* sW = smem + 2048;

  const int tid = threadIdx.x;
  const int l = tid & 63, w = tid >> 6;
  const int qq = l & 15, g = l >> 4;
  const int row = tid >> 2, gp = tid & 3;

  f32x4 acc[4] = {};

  for (int ks = 0; ks < 8; ++ks) {
    const float* xs = X + (size_t)(Mbase + row) * 256 + ks * 32 + gp * 8;
    f32x4 x0 = *(const f32x4*)xs;
    f32x4 x1 = *(const f32x4*)(xs + 4);
    const float* ws_ = W + (size_t)(Nbase + row) * 256 + ks * 32 + gp * 8;
    f32x4 w0 = *(const f32x4*)ws_;
    f32x4 w1 = *(const f32x4*)(ws_ + 4);
    U8 ux, uw;
    ux.u[0] = pack2bf(x0[0], x0[1]); ux.u[1] = pack2bf(x0[2], x0[3]);
    ux.u[2] = pack2bf(x1[0], x1[1]); ux.u[3] = pack2bf(x1[2], x1[3]);
    uw.u[0] = pack2bf(w0[0], w0[1]); uw.u[1] = pack2bf(w0[2], w0[3]);
    uw.u[2] = pack2bf(w1[0], w1[1]); uw.u[3] = pack2bf(w1[2], w1[3]);
    __syncthreads();
    *(bf16x8*)((char*)sX + swz64(row, gp)) = ux.v;
    *(bf16x8*)((char*)sW + swz64(row, gp)) = uw.v;
    __syncthreads();
    bf16x8 a = *(bf16x8*)((char*)sX + swz64(w * 16 + qq, g));
#pragma unroll
    for (int nf = 0; nf < 4; ++nf) {
      bf16x8 bb = *(bf16x8*)((char*)sW + swz64(nf * 16 + qq, g));
      acc[nf] = mfma32(a, bb, acc[nf]);
    }
  }

  if (p == 2) {
    // transpose epilogue -> v_p[B,H,D,K]
    __syncthreads();
#pragma unroll
    for (int nf = 0; nf < 4; ++nf) {
      int n_loc = nf * 16 + qq;
#pragma unroll
      for (int r = 0; r < 4; ++r) {
        int m_loc = w * 16 + 4 * g + r;
        int byte = n_loc * 128 + ((((m_loc >> 3) ^ (n_loc & 7)) << 4)) + (m_loc & 7) * 2;
        *(uint16_t*)((char*)smem + byte) = f2bf(acc[nf][r]);
      }
    }
    __syncthreads();
    const int n_loc = tid >> 2, mp = tid & 3;
    const int ng = Nbase + n_loc;
    const int hh = ng >> 5, dd = ng & 31;
    const int bb_ = Mbase >> 11;
#pragma unroll
    for (int jj = 0; jj < 2; ++jj) {
      int piece = mp * 2 + jj;
      bf16x8 vv = *(bf16x8*)((char*)smem + n_loc * 128 + ((piece ^ (n_loc & 7)) << 4));
      int seq = (Mbase & 2047) + piece * 8;
      *(bf16x8*)(v_p + ((size_t)(bb_ * NH + hh) * ND + dd) * (size_t)HK + seq) = vv;
    }
    return;
  }

#pragma unroll
  for (int nf = 0; nf < 4; ++nf) {
    int n = Nbase + nf * 16 + qq;
#pragma unroll
    for (int r = 0; r < 4; ++r) {
      int m = Mbase + w * 16 + 4 * g + r;
      float val = acc[nf][r];
      if (p == 0) {
        val *= 0.17677669529663687f; // 1/sqrt(32)
        int bb_ = m >> 11, seq = m & 2047, hh = n >> 5, dd = n & 31;
        q_p[((size_t)(bb_ * NH + hh) * HQ + seq) * ND + dd] = f2bf(val);
      } else if (p == 1) {
        int bb_ = m >> 11, seq = m & 2047, hh = n >> 5, dd = n & 31;
        k_p[((size_t)(bb_ * NH + hh) * HK + seq) * ND + dd] = f2bf(val);
      } else { // p == 3 : gate
        g_ws[(size_t)m * NC + n] = 1.f / (1.f + __expf(-(val + bg[n])));
      }
    }
  }
}

// ---------------- fused attention -----------------------------------------
// grid 512 x 512 threads: bx&1 = b, (bx>>1)&7 = h, bx>>4 = q-tile (64 rows)
// 8 waves: waves 0-3 process kt 0..15, waves 4-7 process kt 16..31 (own LDS
// buffers); flash-merge of (m,l,O) partials in the epilogue.
// K/V tiles AND bias_pair fragments are prefetched one iteration ahead.
__global__ __launch_bounds__(512, 4) void attn_kernel(
    const uint16_t* __restrict__ q_p, const uint16_t* __restrict__ k_p,
    const uint16_t* __restrict__ v_p, const float* __restrict__ bias_mask,
    const float* __restrict__ bias_pair, const float* __restrict__ g_ws,
    uint16_t* __restrict__ o_g)
{
  const int bx = blockIdx.x;
  const int b = bx & 1, h = (bx >> 1) & 7, qt = bx >> 4;
  const int bh = b * NH + h;

  __shared__ __align__(16) char smem[16384];

  const int tid = threadIdx.x;
  const int l = tid & 63, w = tid >> 6;
  const int wq = w & 3, half = tid >> 8;   // half == w>>2
  const int qq = l & 15, g = l >> 4;
  const int q_glob = qt * 64 + wq * 16 + qq;

  uint16_t* sK = (uint16_t*)(smem + half * 8192);
  uint16_t* sV = (uint16_t*)(smem + half * 8192 + 4096);

  // Q B-fragment: B[d, q] = q[q, d]; lane: q = l&15, d = g*8..+7  (hoisted)
  bf16x8 qf = *(const bf16x8*)(q_p + ((size_t)bh * HQ + q_glob) * ND + g * 8);

  const int t2 = tid & 255;
  const int krow = t2 >> 2, kgp = t2 & 3;
  const int vrow = t2 >> 3, vgp = t2 & 7;

  f32x4 o0 = {}, o1 = {};
  float m_run = -1e30f, l_run = 0.f;

  const float* bp_base = bias_pair + ((size_t)h * HQ + q_glob) * (size_t)HK;
  const float* bm_base = bias_mask + (size_t)b * HK;

  // ---- prologue: prefetch t = 0 ----
  {
  }
  const int kt0 = half * 16;
  bf16x8 kd = *(const bf16x8*)(k_p + ((size_t)bh * HK + kt0 * 64 + krow) * ND + kgp * 8);
  bf16x8 vd = *(const bf16x8*)(v_p + ((size_t)bh * ND + vrow) * (size_t)HK + kt0 * 64 + vgp * 8);
  f32x4 bpc[4];
#pragma unroll
  for (int F = 0; F < 4; ++F)
    bpc[F] = *(const f32x4*)(bp_base + kt0 * 64 + 32 * (F >> 1) + 8 * g + 4 * (F & 1));

  for (int t = 0; t < 16; ++t) {
    __syncthreads();                         // prev iter's LDS reads done
    *(bf16x8*)((char*)sK + swz64(krow, kgp)) = kd;
    *(bf16x8*)((char*)sV + swzV(vrow, vgp)) = vd;

    // prefetch t+1 (consumed after a full compute phase)
    bf16x8 kdn, vdn; f32x4 bpn[4];
    if (t < 15) {
      const int ktn = half * 16 + t + 1;
      kdn = *(const bf16x8*)(k_p + ((size_t)bh * HK + ktn * 64 + krow) * ND + kgp * 8);
      vdn = *(const bf16x8*)(v_p + ((size_t)bh * ND + vrow) * (size_t)HK + ktn * 64 + vgp * 8);
#pragma unroll
      for (int F = 0; F < 4; ++F)
        bpn[F] = *(const f32x4*)(bp_base + ktn * 64 + 32 * (F >> 1) + 8 * g + 4 * (F & 1));
    }
    __syncthreads();

    // S^T = mfma(K_perm, Q). Row permutation perm(F,i)=32(F>>1)+8(i>>2)+4(F&1)+(i&3)
    // makes the D-layout of P identical to the PV B-fragment layout (no shuffles).
    f32x4 s[4];
#pragma unroll
    for (int F = 0; F < 4; ++F) {
      int kr = 32 * (F >> 1) + 8 * (qq >> 2) + 4 * (F & 1) + (qq & 3);
      bf16x8 af = *(bf16x8*)((char*)sK + swz64(kr, g));
      f32x4 z = {};
      s[F] = mfma32(af, qf, z);
    }
    // biases (k index for frag F, reg r: kt*64 + 32(F>>1) + 8g + 4(F&1) + r)
    const int kt64 = (half * 16 + t) * 64;
    float mloc = -1e30f;
#pragma unroll
    for (int F = 0; F < 4; ++F) {
      f32x4 bm = *(const f32x4*)(bm_base + kt64 + 32 * (F >> 1) + 8 * g + 4 * (F & 1));
#pragma unroll
      for (int r = 0; r < 4; ++r) {
        s[F][r] += bpc[F][r] + bm[r];
        mloc = fmaxf(mloc, s[F][r]);
      }
    }
    mloc = fmaxf(mloc, __shfl_xor(mloc, 16, 64));
    mloc = fmaxf(mloc, __shfl_xor(mloc, 32, 64));
    float m_new = fmaxf(m_run, mloc);
    float alpha = __expf(m_run - m_new);
    float psum = 0.f;
    uint32_t pbk[4][2];
#pragma unroll
    for (int F = 0; F < 4; ++F) {
      float p0 = __expf(s[F][0] - m_new);
      float p1 = __expf(s[F][1] - m_new);
      float p2 = __expf(s[F][2] - m_new);
      float p3 = __expf(s[F][3] - m_new);
      psum += (p0 + p1) + (p2 + p3);
      pbk[F][0] = pack2bf(p0, p1);
      pbk[F][1] = pack2bf(p2, p3);
    }
    psum += __shfl_xor(psum, 16, 64);
    psum += __shfl_xor(psum, 32, 64);
    l_run = l_run * alpha + psum;
    m_run = m_new;
#pragma unroll
    for (int r = 0; r < 4; ++r) { o0[r] *= alpha; o1[r] *= alpha; }

    // O^T += V^T · P^T  (two k-chunks of 32, two d-halves)
#pragma unroll
    for (int c = 0; c < 2; ++c) {
      U8 bu;
      bu.u[0] = pbk[2 * c][0];     bu.u[1] = pbk[2 * c][1];
      bu.u[2] = pbk[2 * c + 1][0]; bu.u[3] = pbk[2 * c + 1][1];
      bf16x8 va0 = *(bf16x8*)((char*)sV + swzV(qq, 4 * c + g));
      bf16x8 va1 = *(bf16x8*)((char*)sV + swzV(16 + qq, 4 * c + g));
      o0 = mfma32(va0, bu.v, o0);
      o1 = mfma32(va1, bu.v, o1);
    }

    if (t < 15) {
      kd = kdn; vd = vdn;
#pragma unroll
      for (int F = 0; F < 4; ++F) bpc[F] = bpn[F];
    }
  }

  // ---- epilogue: flash-merge half1 into half0, then /l, transpose, gate ----
  float* mb = (float*)smem;                 // [4 wq][16 qq][36] f32 = 9216B
  __syncthreads();
  if (half == 1) {
    float* bq = mb + (wq * 16 + qq) * 36;
    if (g == 0) { bq[32] = m_run; bq[33] = l_run; }
#pragma unroll
    for (int r = 0; r < 4; ++r) {
      bq[4 * g + r]      = o0[r];
      bq[16 + 4 * g + r] = o1[r];
    }
  }
  __syncthreads();
  float o0f[4], o1f[4]; float inv = 0.f;
  if (half == 0) {
    const float* bq = mb + (wq * 16 + qq) * 36;
    float mB = bq[32], lB = bq[33];
    float mf = fmaxf(m_run, mB);
    float aA = __expf(m_run - mf), aB = __expf(mB - mf);
    inv = 1.f / (l_run * aA + lB * aB);
#pragma unroll
    for (int r = 0; r < 4; ++r) {
      o0f[r] = o0[r] * aA + bq[4 * g + r] * aB;
      o1f[r] = o1[r] * aA + bq[16 + 4 * g + r] * aB;
    }
  }
  __syncthreads();                           // merge reads done before overwrite
  if (half == 0) {
    float* se = (float*)smem + wq * 576;     // [16 q][36 d] per wave
#pragma unroll
    for (int r = 0; r < 4; ++r) {
      se[qq * 36 + 4 * g + r]      = o0f[r] * inv;   // d = 4g+r
      se[qq * 36 + 16 + 4 * g + r] = o1f[r] * inv;   // d = 16+4g+r
    }
  }
  __syncthreads();
  if (half == 0) {
    const int qrow = l >> 2, pc = l & 3;
    const float* sr = (float*)smem + wq * 576 + qrow * 36 + pc * 8;
    f32x4 x0 = *(const f32x4*)sr;
    f32x4 x1 = *(const f32x4*)(sr + 4);
    const int q_out = qt * 64 + wq * 16 + qrow;
    const float* gp_ = g_ws + ((size_t)b * HQ + q_out) * NC + h * ND + pc * 8;
    f32x4 g0 = *(const f32x4*)gp_;
    f32x4 g1 = *(const f32x4*)(gp_ + 4);
    U8 ou;
    ou.u[0] = pack2bf(x0[0] * g0[0], x0[1] * g0[1]);
    ou.u[1] = pack2bf(x0[2] * g0[2], x0[3] * g0[3]);
    ou.u[2] = pack2bf(x1[0] * g1[0], x1[1] * g1[1]);
    ou.u[3] = pack2bf(x1[2] * g1[2], x1[3] * g1[3]);
    *(bf16x8*)(o_g + ((size_t)b * HQ + q_out) * NC + h * ND + pc * 8) = ou.v;
  }
}

// ---------------- output projection ---------------------------------------
// grid 256: bx&63 = Mblock, bx>>6 = Nblock
__global__ __launch_bounds__(256) void outproj_kernel(
    const uint16_t* __restrict__ o_g, const float* __restrict__ Wo,
    const float* __restrict__ bo, float* __restrict__ out)
{
  const int bx = blockIdx.x;
  const int Mb = bx & 63, Nb = bx >> 6;
  const int Mbase = Mb * 64, Nbase = Nb * 64;
  __shared__ __align__(16) uint16_t smem2[4096];
  uint16_t* sA = smem2;
  uint16_t* sB = smem2 + 2048;
  const int tid = threadIdx.x;
  const int l = tid & 63, w = tid >> 6;
  const int qq = l & 15, g = l >> 4;
  const int row = tid >> 2, gp = tid & 3;
  f32x4 acc[4] = {};
  for (int ks = 0; ks < 8; ++ks) {
    bf16x8 av = *(const bf16x8*)(o_g + (size_t)(Mbase + row) * 256 + ks * 32 + gp * 8);
    const float* wsrc = Wo + (size_t)(Nbase + row) * 256 + ks * 32 + gp * 8;
    f32x4 w0 = *(const f32x4*)wsrc;
    f32x4 w1 = *(const f32x4*)(wsrc + 4);
    U8 uw;
    uw.u[0] = pack2bf(w0[0], w0[1]); uw.u[1] = pack2bf(w0[2], w0[3]);
    uw.u[2] = pack2bf(w1[0], w1[1]); uw.u[3] = pack2bf(w1[2], w1[3]);
    __syncthreads();
    *(bf16x8*)((char*)sA + swz64(row, gp)) = av;
    *(bf16x8*)((char*)sB + swz64(row, gp)) = uw.v;
    __syncthreads();
    bf16x8 a = *(bf16x8*)((char*)sA + swz64(w * 16 + qq, g));
#pragma unroll
    for (int nf = 0; nf < 4; ++nf) {
      bf16x8 bb = *(bf16x8*)((char*)sB + swz64(nf * 16 + qq, g));
      acc[nf] = mfma32(a, bb, acc[nf]);
    }
  }
#pragma unroll
  for (int nf = 0; nf < 4; ++nf) {
    int n = Nbase + nf * 16 + qq;
    float bias = bo[n];
#pragma unroll
    for (int r = 0; r < 4; ++r) {
      int m = Mbase + w * 16 + 4 * g + r;
      out[(size_t)m * NC + n] = acc[nf][r] + bias;
    }
  }
}

extern "C" void kernel_launch(void* const* d_in, const int* in_sizes, int n_in,
                              void* d_out, int out_size, void* d_ws, size_t ws_size,
                              hipStream_t stream) {
  (void)in_sizes; (void)n_in; (void)out_size; (void)ws_size;
  const float* qx        = (const float*)d_in[0];
  const float* kvx       = (const float*)d_in[1];
  const float* bias_mask = (const float*)d_in[2];
  const float* bias_pair = (const float*)d_in[3];
  const float* Wq        = (const float*)d_in[4];
  const float* Wk        = (const float*)d_in[5];
  const float* Wv        = (const float*)d_in[6];
  const float* Wo        = (const float*)d_in[7];
  const float* bo        = (const float*)d_in[8];
  const float* Wg        = (const float*)d_in[9];
  const float* bg        = (const float*)d_in[10];

  char* ws = (char*)d_ws;
  uint16_t* q_p  = (uint16_t*)(ws);                       // 2 MB
  uint16_t* k_p  = (uint16_t*)(ws + (2u << 20));          // 2 MB
  uint16_t* v_p  = (uint16_t*)(ws + (4u << 20));          // 2 MB  [B,H,D,K]
  float*    g_ws = (float*)   (ws + (6u << 20));          // 4 MB
  uint16_t* o_g  = (uint16_t*)(ws + (10u << 20));         // 2 MB
  float* out = (float*)d_out;

  proj_kernel<<<dim3(1024), dim3(256), 0, stream>>>(qx, kvx, Wq, Wk, Wv, Wg, bg,
                                                    q_p, k_p, v_p, g_ws);
  attn_kernel<<<dim3(512), dim3(512), 0, stream>>>(q_p, k_p, v_p, bias_mask,
                                                   bias_pair, g_ws, o_g);
  outproj_kernel<<<dim3(256), dim3(256), 0, stream>>>(o_g, Wo, bo, out);
}